// Round 16
// baseline (1135.700 us; speedup 1.0000x reference)
//
#include <hip/hip_runtime.h>
#include <hip/hip_bf16.h>

#define B_ 16
#define L_ 1024
#define D_ 512
#define K_ 64
#define NL_ 16
#define SMALL_ 8
#define SET_ 128

__device__ inline float waveSum(float v){
#pragma unroll
  for (int o=32;o>0;o>>=1) v += __shfl_down(v,o);
  return v;
}
__device__ inline float waveSumAll(float v){
#pragma unroll
  for (int o=32;o>0;o>>=1) v += __shfl_xor(v,o);
  return v;
}
__device__ inline float waveMax(float v){
#pragma unroll
  for (int o=32;o>0;o>>=1) v = fmaxf(v,__shfl_down(v,o));
  return v;
}

// ---- one-time: Wat[l][d][h] = W_att[l][h][d] ----
__global__ __launch_bounds__(256) void k_wt(const float* __restrict__ W, float* __restrict__ Wt){
  int l = blockIdx.x; int t = threadIdx.x;
  __shared__ float T[64][69];
  const float* src = W + (size_t)l*32768;
  float* dst = Wt + (size_t)l*32768;
  for (int dt=0; dt<8; ++dt){
#pragma unroll
    for (int i=0;i<4;i++){
      int idx=i*256+t; int h=idx>>4, dq=idx&15;
      float4 v = *reinterpret_cast<const float4*>(src + (size_t)h*512 + dt*64 + dq*4);
      T[dq*4+0][h]=v.x; T[dq*4+1][h]=v.y; T[dq*4+2][h]=v.z; T[dq*4+3][h]=v.w;
    }
    __syncthreads();
#pragma unroll
    for (int i=0;i<4;i++){
      int idx=i*256+t; int d=idx>>4, hq=idx&15;
      float4 o;
      o.x=T[d][hq*4+0]; o.y=T[d][hq*4+1]; o.z=T[d][hq*4+2]; o.w=T[d][hq*4+3];
      *reinterpret_cast<float4*>(dst + (size_t)(dt*64+d)*64 + hq*4) = o;
    }
    __syncthreads();
  }
}

// ---- rate GEMM + fused chunk softmax stats (standalone, layer 0) ----
__global__ __launch_bounds__(256) void k_rate_gemm(const float* __restrict__ temb,
    const float* __restrict__ Wat, const float* __restrict__ ba, float* __restrict__ att2,
    float* __restrict__ cmax, float* __restrict__ csum){
  int r0 = blockIdx.x*32;
  __shared__ float As[32][68];
  __shared__ float Bs[64][68];
  __shared__ float OT[32][69];
  __shared__ float pm[4][64];
  __shared__ float cmv[64];
  int t = threadIdx.x;
  int tc = t & 15, tr = t >> 4;
  float acc[2][4] = {{0.f,0.f,0.f,0.f},{0.f,0.f,0.f,0.f}};
  for (int kc=0; kc<512; kc+=64){
#pragma unroll
    for (int i=0;i<2;i++){
      int idx = i*256 + t;
      int row = idx>>4, kq = idx&15;
      *reinterpret_cast<float4*>(&As[row][kq*4]) =
        *reinterpret_cast<const float4*>(temb + (size_t)(r0+row)*512 + kc + kq*4);
    }
#pragma unroll
    for (int i=0;i<4;i++){
      int idx = i*256 + t;
      int k = idx>>4, hq = idx&15;
      *reinterpret_cast<float4*>(&Bs[k][hq*4]) =
        *reinterpret_cast<const float4*>(Wat + (size_t)(kc+k)*64 + hq*4);
    }
    __syncthreads();
#pragma unroll 8
    for (int k=0;k<64;++k){
      float a0 = As[tr*2+0][k];
      float a1 = As[tr*2+1][k];
      float4 b = *reinterpret_cast<const float4*>(&Bs[k][tc*4]);
      acc[0][0]+=a0*b.x; acc[0][1]+=a0*b.y; acc[0][2]+=a0*b.z; acc[0][3]+=a0*b.w;
      acc[1][0]+=a1*b.x; acc[1][1]+=a1*b.y; acc[1][2]+=a1*b.z; acc[1][3]+=a1*b.w;
    }
    __syncthreads();
  }
  float4 bb = *reinterpret_cast<const float4*>(ba + tc*4);
#pragma unroll
  for (int j=0;j<2;j++){
    float4 o;
    o.x = fmaxf(acc[j][0]+bb.x, 0.f);
    o.y = fmaxf(acc[j][1]+bb.y, 0.f);
    o.z = fmaxf(acc[j][2]+bb.z, 0.f);
    o.w = fmaxf(acc[j][3]+bb.w, 0.f);
    *reinterpret_cast<float4*>(att2 + (size_t)(r0 + tr*2 + j)*64 + tc*4) = o;
    OT[tr*2+j][tc*4+0]=o.x; OT[tr*2+j][tc*4+1]=o.y;
    OT[tr*2+j][tc*4+2]=o.z; OT[tr*2+j][tc*4+3]=o.w;
  }
  __syncthreads();
  int h = t & 63, q = t >> 6;
  float m = -1e30f;
#pragma unroll
  for (int r=0;r<8;r++) m = fmaxf(m, OT[q*8+r][h]);
  pm[q][h] = m;
  __syncthreads();
  if (t < 64) cmv[t] = fmaxf(fmaxf(pm[0][t],pm[1][t]),fmaxf(pm[2][t],pm[3][t]));
  __syncthreads();
  float mm = cmv[h];
  float s = 0.f;
#pragma unroll
  for (int r=0;r<8;r++) s += __expf(OT[q*8+r][h]-mm);
  pm[q][h] = s;
  __syncthreads();
  if (t < 64){
    float ss = pm[0][t]+pm[1][t]+pm[2][t]+pm[3][t];
    cmax[(size_t)blockIdx.x*64 + t] = cmv[t];
    csum[(size_t)blockIdx.x*64 + t] = ss;
  }
}

// ---- fused roles, bit-3 interleaved over [0,1024): spart(l) / update(l); [1024,1024+nFi) fi(l-1) ----
__global__ __launch_bounds__(256) void k_su(const float* __restrict__ tembC, float* __restrict__ tembN,
    const float* __restrict__ att2, const float* __restrict__ cmaxi, const float* __restrict__ csumi,
    float* __restrict__ spart,
    const float* __restrict__ wp1, const float* __restrict__ bp1,
    const float* __restrict__ gn, const float* __restrict__ ben,
    float* __restrict__ attdis, int layer,
    const float* __restrict__ fiin_r, const float* __restrict__ Wf, const float* __restrict__ bfi,
    float* __restrict__ resb){
  __shared__ float As[2][32][68];
  __shared__ float Bs[2][32][68];
  __shared__ float smaxS[64], sinvS[64];
  int t = threadIdx.x;
  int bid = blockIdx.x;
  int role = (bid < 1024) ? ((bid >> 3) & 1) : 2;
  int rid  = (bid < 1024) ? (((bid >> 4) << 3) | (bid & 7)) : 0;
  if (role == 0){
    // ---- spart role; double-buffered LDS (one barrier/iter); dt slow (XCD-grouped) ----
    int sid = rid;
    int dt = sid >> 6;            // 0..7 slow
    int g  = sid & 63;            // b*4+lc
    int b = g >> 2, lc = g & 3;
    {
      int k = t & 63;
      float gg = -1e30f;
#pragma unroll 4
      for (int c=0;c<32;c++) gg = fmaxf(gg, cmaxi[(size_t)(b*32+c)*64+k]);
      float s = 0.f;
#pragma unroll 4
      for (int c=0;c<32;c++) s += csumi[(size_t)(b*32+c)*64+k]*__expf(cmaxi[(size_t)(b*32+c)*64+k]-gg);
      if (t < 64){ smaxS[k]=gg; sinvS[k]=1.0f/s; }
    }
    __syncthreads();
    int tc = t & 15, tr = t >> 4;
    int rA = t >> 4;
    int kq4 = (t&15)*4;
    float4 mx = make_float4(smaxS[kq4],smaxS[kq4+1],smaxS[kq4+2],smaxS[kq4+3]);
    float4 iv = make_float4(sinvS[kq4],sinvS[kq4+1],sinvS[kq4+2],sinvS[kq4+3]);
    float acc[4][4] = {{0,0,0,0},{0,0,0,0},{0,0,0,0},{0,0,0,0}};
    int lbase = lc*256;
    {
      float4 a0 = *reinterpret_cast<const float4*>(att2 + ((size_t)(b*L_ + lbase + rA))*64 + kq4);
      float4 a1 = *reinterpret_cast<const float4*>(att2 + ((size_t)(b*L_ + lbase + 16 + rA))*64 + kq4);
      float4 b0 = *reinterpret_cast<const float4*>(tembC + ((size_t)(b*L_) + lbase + rA)*512 + dt*64 + kq4);
      float4 b1 = *reinterpret_cast<const float4*>(tembC + ((size_t)(b*L_) + lbase + 16 + rA)*512 + dt*64 + kq4);
      a0.x=__expf(a0.x-mx.x)*iv.x; a0.y=__expf(a0.y-mx.y)*iv.y;
      a0.z=__expf(a0.z-mx.z)*iv.z; a0.w=__expf(a0.w-mx.w)*iv.w;
      a1.x=__expf(a1.x-mx.x)*iv.x; a1.y=__expf(a1.y-mx.y)*iv.y;
      a1.z=__expf(a1.z-mx.z)*iv.z; a1.w=__expf(a1.w-mx.w)*iv.w;
      *reinterpret_cast<float4*>(&As[0][rA][kq4]) = a0;
      *reinterpret_cast<float4*>(&As[0][16+rA][kq4]) = a1;
      *reinterpret_cast<float4*>(&Bs[0][rA][kq4]) = b0;
      *reinterpret_cast<float4*>(&Bs[0][16+rA][kq4]) = b1;
    }
    __syncthreads();
    int cur = 0;
    for (int ls=0; ls<256; ls+=32){
      int ln = ls + 32;
      float4 qA0, qA1, qB0, qB1;
      bool more = (ln < 256);
      if (more){
        qA0 = *reinterpret_cast<const float4*>(att2 + ((size_t)(b*L_ + lbase + ln + rA))*64 + kq4);
        qA1 = *reinterpret_cast<const float4*>(att2 + ((size_t)(b*L_ + lbase + ln + 16 + rA))*64 + kq4);
        qB0 = *reinterpret_cast<const float4*>(tembC + ((size_t)(b*L_) + lbase + ln + rA)*512 + dt*64 + kq4);
        qB1 = *reinterpret_cast<const float4*>(tembC + ((size_t)(b*L_) + lbase + ln + 16 + rA)*512 + dt*64 + kq4);
      }
#pragma unroll 8
      for (int l=0;l<32;++l){
        float4 a = *reinterpret_cast<const float4*>(&As[cur][l][tr*4]);
        float4 bv = *reinterpret_cast<const float4*>(&Bs[cur][l][tc*4]);
        acc[0][0]+=a.x*bv.x; acc[0][1]+=a.x*bv.y; acc[0][2]+=a.x*bv.z; acc[0][3]+=a.x*bv.w;
        acc[1][0]+=a.y*bv.x; acc[1][1]+=a.y*bv.y; acc[1][2]+=a.y*bv.z; acc[1][3]+=a.y*bv.w;
        acc[2][0]+=a.z*bv.x; acc[2][1]+=a.z*bv.y; acc[2][2]+=a.z*bv.z; acc[2][3]+=a.z*bv.w;
        acc[3][0]+=a.w*bv.x; acc[3][1]+=a.w*bv.y; acc[3][2]+=a.w*bv.z; acc[3][3]+=a.w*bv.w;
      }
      if (more){
        int nxt = cur ^ 1;
        qA0.x=__expf(qA0.x-mx.x)*iv.x; qA0.y=__expf(qA0.y-mx.y)*iv.y;
        qA0.z=__expf(qA0.z-mx.z)*iv.z; qA0.w=__expf(qA0.w-mx.w)*iv.w;
        qA1.x=__expf(qA1.x-mx.x)*iv.x; qA1.y=__expf(qA1.y-mx.y)*iv.y;
        qA1.z=__expf(qA1.z-mx.z)*iv.z; qA1.w=__expf(qA1.w-mx.w)*iv.w;
        *reinterpret_cast<float4*>(&As[nxt][rA][kq4]) = qA0;
        *reinterpret_cast<float4*>(&As[nxt][16+rA][kq4]) = qA1;
        *reinterpret_cast<float4*>(&Bs[nxt][rA][kq4]) = qB0;
        *reinterpret_cast<float4*>(&Bs[nxt][16+rA][kq4]) = qB1;
        cur = nxt;
      }
      __syncthreads();
    }
#pragma unroll
    for (int i=0;i<4;i++){
      float4 o; o.x=acc[i][0]; o.y=acc[i][1]; o.z=acc[i][2]; o.w=acc[i][3];
      *reinterpret_cast<float4*>(&spart[((size_t)((b*4+lc)*64 + tr*4+i))*512 + dt*64 + tc*4]) = o;
    }
  } else if (role == 1){
    // ---- update role; rid mapped so XCD (= bid%8) matches rows' (b,lc) group ----
    int vid = rid;
    int uid = (vid & ~63) | ((vid & 7) << 3) | ((vid >> 3) & 7);
    int r0 = uid*32;
    int b = r0 >> 10;
    {
      int k = t & 63;
      float g = -1e30f;
#pragma unroll 4
      for (int c=0;c<32;c++) g = fmaxf(g, cmaxi[(size_t)(b*32+c)*64+k]);
      float s = 0.f;
#pragma unroll 4
      for (int c=0;c<32;c++) s += csumi[(size_t)(b*32+c)*64+k]*__expf(cmaxi[(size_t)(b*32+c)*64+k]-g);
      if (t < 64){ smaxS[k]=g; sinvS[k]=1.0f/s; }
    }
    __syncthreads();
    int w = t>>6, lane = t&63;
    int d0 = lane*8;
    float4 w0 = *reinterpret_cast<const float4*>(wp1 + d0);
    float4 w1 = *reinterpret_cast<const float4*>(wp1 + d0 + 4);
    float4 p0 = *reinterpret_cast<const float4*>(bp1 + d0);
    float4 p1 = *reinterpret_cast<const float4*>(bp1 + d0 + 4);
    float4 g0 = *reinterpret_cast<const float4*>(gn + d0);
    float4 g1 = *reinterpret_cast<const float4*>(gn + d0 + 4);
    float4 u0 = *reinterpret_cast<const float4*>(ben + d0);
    float4 u1 = *reinterpret_cast<const float4*>(ben + d0 + 4);
    float sm = smaxS[lane], si = sinvS[lane];
    for (int rr=0; rr<8; ++rr){
      int bl = r0 + w*8 + rr;
      float raw = att2[(size_t)bl*64 + lane];
      float a = __expf(raw - sm) * si;
      float sa = waveSumAll(a);
      if (lane==0) attdis[(size_t)(layer*B_ + b)*L_ + (bl & 1023)] = sa;
      const float* sp = tembC + (size_t)bl*512 + d0;
      float4 e0 = *reinterpret_cast<const float4*>(sp);
      float4 e1 = *reinterpret_cast<const float4*>(sp+4);
      float v[8];
      v[0]=e0.x*(sa*w0.x+p0.x+1.f); v[1]=e0.y*(sa*w0.y+p0.y+1.f);
      v[2]=e0.z*(sa*w0.z+p0.z+1.f); v[3]=e0.w*(sa*w0.w+p0.w+1.f);
      v[4]=e1.x*(sa*w1.x+p1.x+1.f); v[5]=e1.y*(sa*w1.y+p1.y+1.f);
      v[6]=e1.z*(sa*w1.z+p1.z+1.f); v[7]=e1.w*(sa*w1.w+p1.w+1.f);
      float s1=0.f, s2=0.f;
#pragma unroll
      for (int j=0;j<8;j++){ s1+=v[j]; s2+=v[j]*v[j]; }
      s1 = waveSumAll(s1); s2 = waveSumAll(s2);
      float m = s1*(1.f/512.f);
      float var = s2*(1.f/512.f) - m*m;
      float rstd = rsqrtf(var+1e-5f);
      float4 o0, o1;
      o0.x=(v[0]-m)*rstd*g0.x+u0.x; o0.y=(v[1]-m)*rstd*g0.y+u0.y;
      o0.z=(v[2]-m)*rstd*g0.z+u0.z; o0.w=(v[3]-m)*rstd*g0.w+u0.w;
      o1.x=(v[4]-m)*rstd*g1.x+u1.x; o1.y=(v[5]-m)*rstd*g1.y+u1.y;
      o1.z=(v[6]-m)*rstd*g1.z+u1.z; o1.w=(v[7]-m)*rstd*g1.w+u1.w;
      float* dp = tembN + (size_t)bl*512 + d0;
      *reinterpret_cast<float4*>(dp)   = o0;
      *reinterpret_cast<float4*>(dp+4) = o1;
    }
  } else {
    // ---- fi(l-1) role ----
    float* row  = &As[0][0][0];
    float* part = &Bs[0][0][0];
    int bf = bid - 1024;
    int oc = bf & 7, b = bf >> 3;
    int og = t & 63, q = t >> 6;
    int o = oc*64 + og;
    reinterpret_cast<float2*>(row)[t] = reinterpret_cast<const float2*>(fiin_r + (size_t)b*512)[t];
    __syncthreads();
    float acc = 0.f;
    const float* wp = Wf + (size_t)(q*128)*512 + o;
    const float* rp = &row[q*128];
#pragma unroll 4
    for (int d=0; d<128; ++d) acc += rp[d] * wp[(size_t)d*512];
    part[q*64+og] = acc;
    __syncthreads();
    if (q==0){
      float s = part[og]+part[64+og]+part[128+og]+part[192+og];
      resb[(size_t)b*512 + o] = fmaxf(s + bfi[o], 0.f) + row[o];
    }
  }
}

// ---- fused roles: [0,nRate) rate(l+1), [nRate,nRate+256) sln(l), then set(l-1) ----
__global__ __launch_bounds__(256) void k_ratesln(const float* __restrict__ tembN,
    const float* __restrict__ Wat, const float* __restrict__ ba, float* __restrict__ att2,
    float* __restrict__ cmax, float* __restrict__ csum,
    const float* __restrict__ spart, const float* __restrict__ ga, const float* __restrict__ bea,
    const float* __restrict__ Wp, const float* __restrict__ bp, float* __restrict__ fiin,
    const float* __restrict__ resb, const float* __restrict__ Ws, const float* __restrict__ bsb,
    float* __restrict__ vecst_l, int nRate){
  __shared__ float As[32][68];
  __shared__ float Bs[64][68];
  __shared__ float OT[32][69];
  __shared__ float pm[4][64];
  __shared__ float cmv[64];
  int t = threadIdx.x;
  if ((int)blockIdx.x < nRate){
    int r0 = blockIdx.x*32;
    int tc = t & 15, tr = t >> 4;
    float acc[2][4] = {{0.f,0.f,0.f,0.f},{0.f,0.f,0.f,0.f}};
    for (int kc=0; kc<512; kc+=64){
#pragma unroll
      for (int i=0;i<2;i++){
        int idx = i*256 + t;
        int row = idx>>4, kq = idx&15;
        *reinterpret_cast<float4*>(&As[row][kq*4]) =
          *reinterpret_cast<const float4*>(tembN + (size_t)(r0+row)*512 + kc + kq*4);
      }
#pragma unroll
      for (int i=0;i<4;i++){
        int idx = i*256 + t;
        int k = idx>>4, hq = idx&15;
        *reinterpret_cast<float4*>(&Bs[k][hq*4]) =
          *reinterpret_cast<const float4*>(Wat + (size_t)(kc+k)*64 + hq*4);
      }
      __syncthreads();
#pragma unroll 8
      for (int k=0;k<64;++k){
        float a0 = As[tr*2+0][k];
        float a1 = As[tr*2+1][k];
        float4 bv = *reinterpret_cast<const float4*>(&Bs[k][tc*4]);
        acc[0][0]+=a0*bv.x; acc[0][1]+=a0*bv.y; acc[0][2]+=a0*bv.z; acc[0][3]+=a0*bv.w;
        acc[1][0]+=a1*bv.x; acc[1][1]+=a1*bv.y; acc[1][2]+=a1*bv.z; acc[1][3]+=a1*bv.w;
      }
      __syncthreads();
    }
    float4 bb = *reinterpret_cast<const float4*>(ba + tc*4);
#pragma unroll
    for (int j=0;j<2;j++){
      float4 o;
      o.x = fmaxf(acc[j][0]+bb.x, 0.f);
      o.y = fmaxf(acc[j][1]+bb.y, 0.f);
      o.z = fmaxf(acc[j][2]+bb.z, 0.f);
      o.w = fmaxf(acc[j][3]+bb.w, 0.f);
      *reinterpret_cast<float4*>(att2 + (size_t)(r0 + tr*2 + j)*64 + tc*4) = o;
      OT[tr*2+j][tc*4+0]=o.x; OT[tr*2+j][tc*4+1]=o.y;
      OT[tr*2+j][tc*4+2]=o.z; OT[tr*2+j][tc*4+3]=o.w;
    }
    __syncthreads();
    int h = t & 63, q = t >> 6;
    float m = -1e30f;
#pragma unroll
    for (int r=0;r<8;r++) m = fmaxf(m, OT[q*8+r][h]);
    pm[q][h] = m;
    __syncthreads();
    if (t < 64) cmv[t] = fmaxf(fmaxf(pm[0][t],pm[1][t]),fmaxf(pm[2][t],pm[3][t]));
    __syncthreads();
    float mm = cmv[h];
    float s = 0.f;
#pragma unroll
    for (int r=0;r<8;r++) s += __expf(OT[q*8+r][h]-mm);
    pm[q][h] = s;
    __syncthreads();
    if (t < 64){
      float ss = pm[0][t]+pm[1][t]+pm[2][t]+pm[3][t];
      cmax[(size_t)blockIdx.x*64 + t] = cmv[t];
      csum[(size_t)blockIdx.x*64 + t] = ss;
    }
  } else if ((int)blockIdx.x < nRate + 256){
    // ---- sln role: 4 waves, one (b,k) each ----
    int gid = blockIdx.x - nRate;
    int w = t>>6, lane = t&63;
    int bk = gid*4 + w;
    int b = bk>>6, k = bk&63;
    int d0 = lane*8;
    float sv[8];
#pragma unroll
    for (int j=0;j<8;j++) sv[j]=0.f;
#pragma unroll
    for (int lc=0;lc<4;lc++){
      const float* p = spart + ((size_t)((b*4+lc)*64 + k))*512 + d0;
      float4 x0 = *reinterpret_cast<const float4*>(p);
      float4 x1 = *reinterpret_cast<const float4*>(p+4);
      sv[0]+=x0.x; sv[1]+=x0.y; sv[2]+=x0.z; sv[3]+=x0.w;
      sv[4]+=x1.x; sv[5]+=x1.y; sv[6]+=x1.z; sv[7]+=x1.w;
    }
    const float inv_sqrt_L = 0.03125f;
    float s1=0.f, s2=0.f;
#pragma unroll
    for (int j=0;j<8;j++){ sv[j]*=inv_sqrt_L; s1+=sv[j]; s2+=sv[j]*sv[j]; }
    s1 = waveSumAll(s1); s2 = waveSumAll(s2);
    float m = s1*(1.0f/512.0f);
    float var = s2*(1.0f/512.0f) - m*m;
    float rstd = rsqrtf(var + 1e-5f);
    const float* gap = ga + (size_t)k*512 + d0;
    const float* bep = bea + (size_t)k*512 + d0;
    float4 g0 = *reinterpret_cast<const float4*>(gap);
    float4 g1 = *reinterpret_cast<const float4*>(gap+4);
    float4 e0 = *reinterpret_cast<const float4*>(bep);
    float4 e1 = *reinterpret_cast<const float4*>(bep+4);
    float gav[8] = {g0.x,g0.y,g0.z,g0.w,g1.x,g1.y,g1.z,g1.w};
    float bev[8] = {e0.x,e0.y,e0.z,e0.w,e1.x,e1.y,e1.z,e1.w};
    float acc[8];
#pragma unroll
    for (int e=0;e<8;e++) acc[e]=0.f;
#pragma unroll
    for (int j=0;j<8;j++){
      float sl = (sv[j]-m)*rstd*gav[j] + bev[j];
      const float* wp = Wp + ((size_t)k*512 + d0 + j)*8;
      float4 w0 = *reinterpret_cast<const float4*>(wp);
      float4 w1 = *reinterpret_cast<const float4*>(wp+4);
      acc[0]+=sl*w0.x; acc[1]+=sl*w0.y; acc[2]+=sl*w0.z; acc[3]+=sl*w0.w;
      acc[4]+=sl*w1.x; acc[5]+=sl*w1.y; acc[6]+=sl*w1.z; acc[7]+=sl*w1.w;
    }
#pragma unroll
    for (int e=0;e<8;e++) acc[e] = waveSum(acc[e]);
    if (lane==0){
#pragma unroll
      for (int e=0;e<8;e++)
        fiin[(size_t)b*512 + e*64 + k] = fmaxf(acc[e] + bp[k*8+e], 0.f);
    }
  } else {
    // ---- set(l-1) role ----
    float* row  = &As[0][0];
    float* part = &OT[0][0];
    int bsI = blockIdx.x - nRate - 256;
    int oc = bsI & 1, b = bsI >> 1;
    int og = t & 63, q = t >> 6;
    int o = oc*64 + og;
    reinterpret_cast<float2*>(row)[t] = reinterpret_cast<const float2*>(resb + (size_t)b*512)[t];
    __syncthreads();
    float acc = 0.f;
    const float* wp = Ws + (size_t)(q*128)*128 + o;
    const float* rp = &row[q*128];
#pragma unroll 4
    for (int d=0; d<128; ++d) acc += rp[d] * wp[(size_t)d*128];
    part[q*64+og] = acc;
    __syncthreads();
    if (q==0){
      vecst_l[(size_t)b*128 + o] = fmaxf(part[og]+part[64+og]+part[128+og]+part[192+og] + bsb[o], 0.f);
    }
  }
}

// ---- standalone FI (tail, layer 15) ----
__global__ __launch_bounds__(256) void k_fi(const float* __restrict__ fiin,
    const float* __restrict__ Wf, const float* __restrict__ bfi, float* __restrict__ res){
  int oc = blockIdx.x, b = blockIdx.y;
  int tid = threadIdx.x;
  int og = tid & 63, q = tid >> 6;
  int o = oc*64 + og;
  __shared__ float row[512];
  __shared__ float part[4][64];
  reinterpret_cast<float2*>(row)[tid] = reinterpret_cast<const float2*>(fiin + (size_t)b*512)[tid];
  __syncthreads();
  float acc = 0.f;
  const float* wp = Wf + (size_t)(q*128)*512 + o;
  const float* rp = &row[q*128];
#pragma unroll 4
  for (int d=0; d<128; ++d) acc += rp[d] * wp[(size_t)d*512];
  part[q][og] = acc;
  __syncthreads();
  if (q==0){
    float s = part[0][og]+part[1][og]+part[2][og]+part[3][og];
    res[(size_t)b*512 + o] = fmaxf(s + bfi[o], 0.f) + row[o];
  }
}

// ---- standalone Set (tail, layer 15) ----
__global__ __launch_bounds__(256) void k_set(const float* __restrict__ res,
    const float* __restrict__ Ws, const float* __restrict__ bs, float* __restrict__ vecst_l){
  int oc = blockIdx.x, b = blockIdx.y;
  int tid = threadIdx.x;
  int og = tid & 63, q = tid >> 6;
  int o = oc*64 + og;
  __shared__ float row[512];
  __shared__ float part[4][64];
  reinterpret_cast<float2*>(row)[tid] = reinterpret_cast<const float2*>(res + (size_t)b*512)[tid];
  __syncthreads();
  float acc = 0.f;
  const float* wp = Ws + (size_t)(q*128)*128 + o;
  const float* rp = &row[q*128];
#pragma unroll 4
  for (int d=0; d<128; ++d) acc += rp[d] * wp[(size_t)d*128];
  part[q][og] = acc;
  __syncthreads();
  if (q==0){
    vecst_l[(size_t)b*128 + o] = fmaxf(part[0][og]+part[1][og]+part[2][og]+part[3][og] + bs[o], 0.f);
  }
}

// ---- final attention rate (wave-per-row) ----
__global__ __launch_bounds__(256) void k_aat_rate(const float* __restrict__ temb,
    const float* __restrict__ w_aat, const float* __restrict__ b_aat, float* __restrict__ ratef){
  int w = threadIdx.x>>6, lane = threadIdx.x&63;
  int bl = blockIdx.x*4 + w;
  const float* rp = temb + (size_t)bl*512 + lane*8;
  float4 e0 = *reinterpret_cast<const float4*>(rp);
  float4 e1 = *reinterpret_cast<const float4*>(rp+4);
  const float* wp = w_aat + lane*8;
  float4 w0 = *reinterpret_cast<const float4*>(wp);
  float4 w1 = *reinterpret_cast<const float4*>(wp+4);
  float s = e0.x*w0.x+e0.y*w0.y+e0.z*w0.z+e0.w*w0.w
          + e1.x*w1.x+e1.y*w1.y+e1.z*w1.z+e1.w*w1.w;
  s = waveSum(s);
  if (lane==0) ratef[bl] = fmaxf(s + b_aat[0], 0.f);
}

// ---- softmax over a contiguous 1024-run per block ----
__global__ __launch_bounds__(256) void k_softmax_seq(float* __restrict__ ratef){
  int b = blockIdx.x; int tid = threadIdx.x;
  float* base = ratef + (size_t)b*1024;
  float4 v = reinterpret_cast<float4*>(base)[tid];
  float mx = fmaxf(fmaxf(v.x,v.y),fmaxf(v.z,v.w));
  __shared__ float red[8];
  int wave=tid>>6, lane=tid&63;
  float wm = waveMax(mx);
  if(lane==0) red[wave]=wm;
  __syncthreads();
  mx = fmaxf(fmaxf(red[0],red[1]),fmaxf(red[2],red[3]));
  v.x=__expf(v.x-mx); v.y=__expf(v.y-mx); v.z=__expf(v.z-mx); v.w=__expf(v.w-mx);
  float s = v.x+v.y+v.z+v.w;
  float wsum = waveSum(s);
  if(lane==0) red[4+wave]=wsum;
  __syncthreads();
  s = red[4]+red[5]+red[6]+red[7];
  float inv = 1.f/s;
  v.x*=inv;v.y*=inv;v.z*=inv;v.w*=inv;
  reinterpret_cast<float4*>(base)[tid] = v;
}

// ---- final pool partials ----
__global__ __launch_bounds__(256) void k_poolA(const float* __restrict__ temb, const float* __restrict__ attf,
                                               float* __restrict__ sraw){
  int dc = blockIdx.x, b = blockIdx.y;
  int tid = threadIdx.x;
  int dl = tid & 63, q = tid >> 6;
  int d = dc*64 + dl;
  __shared__ float sA[1024];
  __shared__ float part[4][64];
  reinterpret_cast<float4*>(sA)[tid] = reinterpret_cast<const float4*>(attf + (size_t)b*1024)[tid];
  __syncthreads();
  float acc = 0.f;
  const float* tp = temb + ((size_t)b*1024 + q*256)*512 + d;
  const float* ap = &sA[q*256];
#pragma unroll 4
  for (int l=0;l<256;++l) acc += tp[(size_t)l*512]*ap[l];
  part[q][dl] = acc;
  __syncthreads();
  if (q==0) sraw[(size_t)b*512 + d] = (part[0][dl]+part[1][dl]+part[2][dl]+part[3][dl])*0.03125f;
}

// ---- final pool LN ----
__global__ __launch_bounds__(256) void k_poolB(const float* __restrict__ sraw,
   const float* __restrict__ g_aat, const float* __restrict__ be_aat, float* __restrict__ spool){
  int b = blockIdx.x; int tid = threadIdx.x;
  int d0 = tid*2;
  float2 a = *reinterpret_cast<const float2*>(&sraw[(size_t)b*512 + d0]);
  __shared__ float red[8];
  int wave=tid>>6,lane=tid&63;
  float s1 = a.x+a.y, s2 = a.x*a.x+a.y*a.y;
  float w1=waveSum(s1), w2=waveSum(s2);
  if(lane==0){red[wave]=w1; red[4+wave]=w2;}
  __syncthreads();
  s1=red[0]+red[1]+red[2]+red[3];
  s2=red[4]+red[5]+red[6]+red[7];
  float m=s1*(1.f/512.f), var=s2*(1.f/512.f)-m*m, rstd=rsqrtf(var+1e-5f);
  float2 ug=*reinterpret_cast<const float2*>(g_aat+d0);
  float2 ub=*reinterpret_cast<const float2*>(be_aat+d0);
  spool[(size_t)b*512+d0]   = (a.x-m)*rstd*ug.x+ub.x;
  spool[(size_t)b*512+d0+1] = (a.y-m)*rstd*ug.y+ub.y;
}

// ---- final head ----
__global__ __launch_bounds__(256) void k_final(const float* __restrict__ spool, const float* __restrict__ vecst,
    const float* __restrict__ Wh, const float* __restrict__ bh, float* __restrict__ Pout){
  int b = blockIdx.x; int tid = threadIdx.x;
  float part = 0.f;
  for (int i = tid; i < 2560; i += 256){
    float v;
    if (i < 512) v = spool[(size_t)b*512 + i];
    else {
      int j = i - 512;
      v = vecst[(size_t)(j>>7)*(B_*SET_) + b*SET_ + (j&127)];
    }
    part += v * Wh[i];
  }
  __shared__ float red[4];
  int wave=tid>>6,lane=tid&63;
  float w = waveSum(part);
  if(lane==0) red[wave]=w;
  __syncthreads();
  if (tid==0){
    float x = red[0]+red[1]+red[2]+red[3] + bh[0];
    Pout[b] = 1.0f/(1.0f+expf(-x));
  }
}

extern "C" void kernel_launch(void* const* d_in, const int* in_sizes, int n_in,
                              void* d_out, int out_size, void* d_ws, size_t ws_size,
                              hipStream_t stream){
  const float* emb   = (const float*)d_in[0];
  const float* W_att = (const float*)d_in[1];
  const float* b_att = (const float*)d_in[2];
  const float* g_att = (const float*)d_in[3];
  const float* be_att= (const float*)d_in[4];
  const float* W_pro = (const float*)d_in[5];
  const float* b_pro = (const float*)d_in[6];
  const float* w_p1  = (const float*)d_in[7];
  const float* b_p1  = (const float*)d_in[8];
  const float* W_FI  = (const float*)d_in[9];
  const float* b_FI  = (const float*)d_in[10];
  const float* W_Set = (const float*)d_in[11];
  const float* b_Set = (const float*)d_in[12];
  const float* g_n   = (const float*)d_in[13];
  const float* be_n  = (const float*)d_in[14];
  const float* w_aat = (const float*)d_in[15];
  const float* b_aat = (const float*)d_in[16];
  const float* g_aat = (const float*)d_in[17];
  const float* be_aat= (const float*)d_in[18];
  const float* W_h2p = (const float*)d_in[19];
  const float* b_h2p = (const float*)d_in[20];
  float* out = (float*)d_out;

  float* ws = (float*)d_ws;
  float* temb0 = ws;                      // 8,388,608
  float* temb1 = temb0 + 8388608;         // 8,388,608
  float* att2  = temb1 + 8388608;         // 1,048,576
  float* spart = att2 + 1048576;          // 2,097,152
  float* fiin  = spart + 2097152;         // 8,192
  float* vecst = fiin + 8192;             // 131,072
  float* ratef = vecst + 131072;          // 16,384
  float* spool = ratef + 16384;           // 8,192
  float* res   = spool + 8192;            // 8,192
  float* sraw  = res + 8192;              // 8,192
  float* Wat   = sraw + 8192;             // 524,288
  float* cmaxA = Wat + 524288;            // 32,768
  float* csumA = cmaxA + 32768;           // 32,768

  k_wt<<<16,256,0,stream>>>(W_att, Wat);
  k_rate_gemm<<<512,256,0,stream>>>(emb, Wat, b_att, att2, cmaxA, csumA);
  for (int l=0; l<16; ++l){
    const float* tcur = (l==0) ? emb : ((l&1) ? temb0 : temb1);
    float* tnxt = (l&1) ? temb1 : temb0;
    int nFi = (l>0) ? 128 : 0;
    int lprev = (l>0) ? (l-1) : 0;
    k_su<<<1024+nFi,256,0,stream>>>(tcur, tnxt, att2, cmaxA, csumA, spart,
                                    w_p1 + l*512, b_p1 + l*512, g_n + l*512, be_n + l*512,
                                    out + 16, l,
                                    fiin, W_FI + (size_t)lprev*262144, b_FI + lprev*512, res);
    int nRate = (l < 15) ? 512 : 0;
    int nSet = (l>0) ? 32 : 0;
    k_ratesln<<<nRate + 256 + nSet,256,0,stream>>>(tnxt, Wat + (size_t)(l+1)*32768, b_att + (l+1)*64,
                                            att2, cmaxA, csumA,
                                            spart, g_att + (size_t)l*32768, be_att + (size_t)l*32768,
                                            W_pro + (size_t)l*262144, b_pro + l*512, fiin,
                                            res, W_Set + (size_t)lprev*65536, b_Set + lprev*128,
                                            vecst + (size_t)lprev*2048, nRate);
  }
  // tail: fi(15) + set(15)
  k_fi<<<dim3(8,16),256,0,stream>>>(fiin, W_FI + (size_t)15*262144, b_FI + 15*512, res);
  k_set<<<dim3(2,16),256,0,stream>>>(res, W_Set + (size_t)15*65536, b_Set + 15*128,
                                     vecst + (size_t)15*2048);
  float* tfin = temb1;   // layer 15 writes temb1
  k_aat_rate<<<4096,256,0,stream>>>(tfin, w_aat, b_aat, ratef);
  k_softmax_seq<<<16,256,0,stream>>>(ratef);
  k_poolA<<<dim3(8,16),256,0,stream>>>(tfin, ratef, sraw);
  k_poolB<<<16,256,0,stream>>>(sraw, g_aat, be_aat, spool);
  k_final<<<16,256,0,stream>>>(spool, vecst, W_h2p, b_h2p, out);
}

// Round 17
// 1008.364 us; speedup vs baseline: 1.1263x; 1.1263x over previous
//
#include <hip/hip_runtime.h>
#include <hip/hip_bf16.h>

#define B_ 16
#define L_ 1024
#define D_ 512
#define K_ 64
#define NL_ 16
#define SMALL_ 8
#define SET_ 128

__device__ inline float waveSum(float v){
#pragma unroll
  for (int o=32;o>0;o>>=1) v += __shfl_down(v,o);
  return v;
}
__device__ inline float waveSumAll(float v){
#pragma unroll
  for (int o=32;o>0;o>>=1) v += __shfl_xor(v,o);
  return v;
}
__device__ inline float waveMax(float v){
#pragma unroll
  for (int o=32;o>0;o>>=1) v = fmaxf(v,__shfl_down(v,o));
  return v;
}

// ---- one-time: Wat[l][d][h] = W_att[l][h][d] ----
__global__ __launch_bounds__(256) void k_wt(const float* __restrict__ W, float* __restrict__ Wt){
  int l = blockIdx.x; int t = threadIdx.x;
  __shared__ float T[64][69];
  const float* src = W + (size_t)l*32768;
  float* dst = Wt + (size_t)l*32768;
  for (int dt=0; dt<8; ++dt){
#pragma unroll
    for (int i=0;i<4;i++){
      int idx=i*256+t; int h=idx>>4, dq=idx&15;
      float4 v = *reinterpret_cast<const float4*>(src + (size_t)h*512 + dt*64 + dq*4);
      T[dq*4+0][h]=v.x; T[dq*4+1][h]=v.y; T[dq*4+2][h]=v.z; T[dq*4+3][h]=v.w;
    }
    __syncthreads();
#pragma unroll
    for (int i=0;i<4;i++){
      int idx=i*256+t; int d=idx>>4, hq=idx&15;
      float4 o;
      o.x=T[d][hq*4+0]; o.y=T[d][hq*4+1]; o.z=T[d][hq*4+2]; o.w=T[d][hq*4+3];
      *reinterpret_cast<float4*>(dst + (size_t)(dt*64+d)*64 + hq*4) = o;
    }
    __syncthreads();
  }
}

// ---- rate GEMM + fused chunk softmax stats (standalone, layer 0) ----
__global__ __launch_bounds__(256) void k_rate_gemm(const float* __restrict__ temb,
    const float* __restrict__ Wat, const float* __restrict__ ba, float* __restrict__ att2,
    float* __restrict__ cmax, float* __restrict__ csum){
  int r0 = blockIdx.x*32;
  __shared__ float As[32][68];
  __shared__ float Bs[64][68];
  __shared__ float OT[32][69];
  __shared__ float pm[4][64];
  __shared__ float cmv[64];
  int t = threadIdx.x;
  int tc = t & 15, tr = t >> 4;
  float acc[2][4] = {{0.f,0.f,0.f,0.f},{0.f,0.f,0.f,0.f}};
  for (int kc=0; kc<512; kc+=64){
#pragma unroll
    for (int i=0;i<2;i++){
      int idx = i*256 + t;
      int row = idx>>4, kq = idx&15;
      *reinterpret_cast<float4*>(&As[row][kq*4]) =
        *reinterpret_cast<const float4*>(temb + (size_t)(r0+row)*512 + kc + kq*4);
    }
#pragma unroll
    for (int i=0;i<4;i++){
      int idx = i*256 + t;
      int k = idx>>4, hq = idx&15;
      *reinterpret_cast<float4*>(&Bs[k][hq*4]) =
        *reinterpret_cast<const float4*>(Wat + (size_t)(kc+k)*64 + hq*4);
    }
    __syncthreads();
#pragma unroll 8
    for (int k=0;k<64;++k){
      float a0 = As[tr*2+0][k];
      float a1 = As[tr*2+1][k];
      float4 b = *reinterpret_cast<const float4*>(&Bs[k][tc*4]);
      acc[0][0]+=a0*b.x; acc[0][1]+=a0*b.y; acc[0][2]+=a0*b.z; acc[0][3]+=a0*b.w;
      acc[1][0]+=a1*b.x; acc[1][1]+=a1*b.y; acc[1][2]+=a1*b.z; acc[1][3]+=a1*b.w;
    }
    __syncthreads();
  }
  float4 bb = *reinterpret_cast<const float4*>(ba + tc*4);
#pragma unroll
  for (int j=0;j<2;j++){
    float4 o;
    o.x = fmaxf(acc[j][0]+bb.x, 0.f);
    o.y = fmaxf(acc[j][1]+bb.y, 0.f);
    o.z = fmaxf(acc[j][2]+bb.z, 0.f);
    o.w = fmaxf(acc[j][3]+bb.w, 0.f);
    *reinterpret_cast<float4*>(att2 + (size_t)(r0 + tr*2 + j)*64 + tc*4) = o;
    OT[tr*2+j][tc*4+0]=o.x; OT[tr*2+j][tc*4+1]=o.y;
    OT[tr*2+j][tc*4+2]=o.z; OT[tr*2+j][tc*4+3]=o.w;
  }
  __syncthreads();
  int h = t & 63, q = t >> 6;
  float m = -1e30f;
#pragma unroll
  for (int r=0;r<8;r++) m = fmaxf(m, OT[q*8+r][h]);
  pm[q][h] = m;
  __syncthreads();
  if (t < 64) cmv[t] = fmaxf(fmaxf(pm[0][t],pm[1][t]),fmaxf(pm[2][t],pm[3][t]));
  __syncthreads();
  float mm = cmv[h];
  float s = 0.f;
#pragma unroll
  for (int r=0;r<8;r++) s += __expf(OT[q*8+r][h]-mm);
  pm[q][h] = s;
  __syncthreads();
  if (t < 64){
    float ss = pm[0][t]+pm[1][t]+pm[2][t]+pm[3][t];
    cmax[(size_t)blockIdx.x*64 + t] = cmv[t];
    csum[(size_t)blockIdx.x*64 + t] = ss;
  }
}

// ---- fused roles: [0,512) spart(l) (XCD-grouped, prefetched), [512,1024) update(l), [1024,1024+nFi) fi(l-1) ----
__global__ __launch_bounds__(256) void k_su(const float* __restrict__ tembC, float* __restrict__ tembN,
    const float* __restrict__ att2, const float* __restrict__ cmaxi, const float* __restrict__ csumi,
    float* __restrict__ spart,
    const float* __restrict__ wp1, const float* __restrict__ bp1,
    const float* __restrict__ gn, const float* __restrict__ ben,
    float* __restrict__ attdis, int layer,
    const float* __restrict__ fiin_r, const float* __restrict__ Wf, const float* __restrict__ bfi,
    float* __restrict__ resb){
  __shared__ float As[32][68];
  __shared__ float Bs[32][68];
  __shared__ float smaxS[64], sinvS[64];
  int t = threadIdx.x;
  if (blockIdx.x < 512){
    // ---- spart role; dt slow so the 8 dt-blocks of one (b,lc) att-tile share blockIdx%8 (same XCD L2) ----
    int sid = blockIdx.x;
    int dt = sid >> 6;            // 0..7 slow
    int g  = sid & 63;            // b*4+lc ; XCD = sid%8 = g%8 const across dt
    int b = g >> 2, lc = g & 3;
    {
      int k = t & 63;
      float gg = -1e30f;
#pragma unroll 4
      for (int c=0;c<32;c++) gg = fmaxf(gg, cmaxi[(size_t)(b*32+c)*64+k]);
      float s = 0.f;
#pragma unroll 4
      for (int c=0;c<32;c++) s += csumi[(size_t)(b*32+c)*64+k]*__expf(cmaxi[(size_t)(b*32+c)*64+k]-gg);
      if (t < 64){ smaxS[k]=gg; sinvS[k]=1.0f/s; }
    }
    __syncthreads();
    int tc = t & 15, tr = t >> 4;
    int rA = t >> 4;              // staging row 0..15 (and +16)
    int kq4 = (t&15)*4;
    float4 mx = make_float4(smaxS[kq4],smaxS[kq4+1],smaxS[kq4+2],smaxS[kq4+3]);
    float4 iv = make_float4(sinvS[kq4],sinvS[kq4+1],sinvS[kq4+2],sinvS[kq4+3]);
    float acc[4][4] = {{0,0,0,0},{0,0,0,0},{0,0,0,0},{0,0,0,0}};
    int lbase = lc*256;
    float4 pA0, pA1, pB0, pB1;
    pA0 = *reinterpret_cast<const float4*>(att2 + ((size_t)(b*L_ + lbase + rA))*64 + kq4);
    pA1 = *reinterpret_cast<const float4*>(att2 + ((size_t)(b*L_ + lbase + 16 + rA))*64 + kq4);
    pB0 = *reinterpret_cast<const float4*>(tembC + ((size_t)(b*L_) + lbase + rA)*512 + dt*64 + kq4);
    pB1 = *reinterpret_cast<const float4*>(tembC + ((size_t)(b*L_) + lbase + 16 + rA)*512 + dt*64 + kq4);
    for (int ls=0; ls<256; ls+=32){
      float4 va = pA0;
      va.x=__expf(va.x-mx.x)*iv.x; va.y=__expf(va.y-mx.y)*iv.y;
      va.z=__expf(va.z-mx.z)*iv.z; va.w=__expf(va.w-mx.w)*iv.w;
      *reinterpret_cast<float4*>(&As[rA][kq4]) = va;
      float4 vb = pA1;
      vb.x=__expf(vb.x-mx.x)*iv.x; vb.y=__expf(vb.y-mx.y)*iv.y;
      vb.z=__expf(vb.z-mx.z)*iv.z; vb.w=__expf(vb.w-mx.w)*iv.w;
      *reinterpret_cast<float4*>(&As[16+rA][kq4]) = vb;
      *reinterpret_cast<float4*>(&Bs[rA][kq4]) = pB0;
      *reinterpret_cast<float4*>(&Bs[16+rA][kq4]) = pB1;
      __syncthreads();
      int ln = ls + 32;
      if (ln < 256){
        pA0 = *reinterpret_cast<const float4*>(att2 + ((size_t)(b*L_ + lbase + ln + rA))*64 + kq4);
        pA1 = *reinterpret_cast<const float4*>(att2 + ((size_t)(b*L_ + lbase + ln + 16 + rA))*64 + kq4);
        pB0 = *reinterpret_cast<const float4*>(tembC + ((size_t)(b*L_) + lbase + ln + rA)*512 + dt*64 + kq4);
        pB1 = *reinterpret_cast<const float4*>(tembC + ((size_t)(b*L_) + lbase + ln + 16 + rA)*512 + dt*64 + kq4);
      }
#pragma unroll 8
      for (int l=0;l<32;++l){
        float4 a = *reinterpret_cast<const float4*>(&As[l][tr*4]);
        float4 bv = *reinterpret_cast<const float4*>(&Bs[l][tc*4]);
        acc[0][0]+=a.x*bv.x; acc[0][1]+=a.x*bv.y; acc[0][2]+=a.x*bv.z; acc[0][3]+=a.x*bv.w;
        acc[1][0]+=a.y*bv.x; acc[1][1]+=a.y*bv.y; acc[1][2]+=a.y*bv.z; acc[1][3]+=a.y*bv.w;
        acc[2][0]+=a.z*bv.x; acc[2][1]+=a.z*bv.y; acc[2][2]+=a.z*bv.z; acc[2][3]+=a.z*bv.w;
        acc[3][0]+=a.w*bv.x; acc[3][1]+=a.w*bv.y; acc[3][2]+=a.w*bv.z; acc[3][3]+=a.w*bv.w;
      }
      __syncthreads();
    }
#pragma unroll
    for (int i=0;i<4;i++){
      float4 o; o.x=acc[i][0]; o.y=acc[i][1]; o.z=acc[i][2]; o.w=acc[i][3];
      *reinterpret_cast<float4*>(&spart[((size_t)((b*4+lc)*64 + tr*4+i))*512 + dt*64 + tc*4]) = o;
    }
  } else if (blockIdx.x < 1024){
    // ---- update role; bit-swap so rows' (b,lc) group XCD matches spart's ----
    int vid = blockIdx.x - 512;
    int uid = (vid & ~63) | ((vid & 7) << 3) | ((vid >> 3) & 7);
    int r0 = uid*32;
    int b = r0 >> 10;
    {
      int k = t & 63;
      float g = -1e30f;
#pragma unroll 4
      for (int c=0;c<32;c++) g = fmaxf(g, cmaxi[(size_t)(b*32+c)*64+k]);
      float s = 0.f;
#pragma unroll 4
      for (int c=0;c<32;c++) s += csumi[(size_t)(b*32+c)*64+k]*__expf(cmaxi[(size_t)(b*32+c)*64+k]-g);
      if (t < 64){ smaxS[k]=g; sinvS[k]=1.0f/s; }
    }
    __syncthreads();
    int w = t>>6, lane = t&63;
    int d0 = lane*8;
    float4 w0 = *reinterpret_cast<const float4*>(wp1 + d0);
    float4 w1 = *reinterpret_cast<const float4*>(wp1 + d0 + 4);
    float4 p0 = *reinterpret_cast<const float4*>(bp1 + d0);
    float4 p1 = *reinterpret_cast<const float4*>(bp1 + d0 + 4);
    float4 g0 = *reinterpret_cast<const float4*>(gn + d0);
    float4 g1 = *reinterpret_cast<const float4*>(gn + d0 + 4);
    float4 u0 = *reinterpret_cast<const float4*>(ben + d0);
    float4 u1 = *reinterpret_cast<const float4*>(ben + d0 + 4);
    float sm = smaxS[lane], si = sinvS[lane];
    for (int rr=0; rr<8; ++rr){
      int bl = r0 + w*8 + rr;
      float raw = att2[(size_t)bl*64 + lane];
      float a = __expf(raw - sm) * si;
      float sa = waveSumAll(a);
      if (lane==0) attdis[(size_t)(layer*B_ + b)*L_ + (bl & 1023)] = sa;
      const float* sp = tembC + (size_t)bl*512 + d0;
      float4 e0 = *reinterpret_cast<const float4*>(sp);
      float4 e1 = *reinterpret_cast<const float4*>(sp+4);
      float v[8];
      v[0]=e0.x*(sa*w0.x+p0.x+1.f); v[1]=e0.y*(sa*w0.y+p0.y+1.f);
      v[2]=e0.z*(sa*w0.z+p0.z+1.f); v[3]=e0.w*(sa*w0.w+p0.w+1.f);
      v[4]=e1.x*(sa*w1.x+p1.x+1.f); v[5]=e1.y*(sa*w1.y+p1.y+1.f);
      v[6]=e1.z*(sa*w1.z+p1.z+1.f); v[7]=e1.w*(sa*w1.w+p1.w+1.f);
      float s1=0.f, s2=0.f;
#pragma unroll
      for (int j=0;j<8;j++){ s1+=v[j]; s2+=v[j]*v[j]; }
      s1 = waveSumAll(s1); s2 = waveSumAll(s2);
      float m = s1*(1.f/512.f);
      float var = s2*(1.f/512.f) - m*m;
      float rstd = rsqrtf(var+1e-5f);
      float4 o0, o1;
      o0.x=(v[0]-m)*rstd*g0.x+u0.x; o0.y=(v[1]-m)*rstd*g0.y+u0.y;
      o0.z=(v[2]-m)*rstd*g0.z+u0.z; o0.w=(v[3]-m)*rstd*g0.w+u0.w;
      o1.x=(v[4]-m)*rstd*g1.x+u1.x; o1.y=(v[5]-m)*rstd*g1.y+u1.y;
      o1.z=(v[6]-m)*rstd*g1.z+u1.z; o1.w=(v[7]-m)*rstd*g1.w+u1.w;
      float* dp = tembN + (size_t)bl*512 + d0;
      *reinterpret_cast<float4*>(dp)   = o0;
      *reinterpret_cast<float4*>(dp+4) = o1;
    }
  } else {
    // ---- fi(l-1) role ----
    float* row  = &As[0][0];
    float* part = &Bs[0][0];
    int bf = blockIdx.x - 1024;
    int oc = bf & 7, b = bf >> 3;
    int og = t & 63, q = t >> 6;
    int o = oc*64 + og;
    reinterpret_cast<float2*>(row)[t] = reinterpret_cast<const float2*>(fiin_r + (size_t)b*512)[t];
    __syncthreads();
    float acc = 0.f;
    const float* wp = Wf + (size_t)(q*128)*512 + o;
    const float* rp = &row[q*128];
#pragma unroll 4
    for (int d=0; d<128; ++d) acc += rp[d] * wp[(size_t)d*512];
    part[q*64+og] = acc;
    __syncthreads();
    if (q==0){
      float s = part[og]+part[64+og]+part[128+og]+part[192+og];
      resb[(size_t)b*512 + o] = fmaxf(s + bfi[o], 0.f) + row[o];
    }
  }
}

// ---- fused roles: [0,nRate) rate(l+1), [nRate,nRate+256) sln(l), then set(l-1) ----
__global__ __launch_bounds__(256) void k_ratesln(const float* __restrict__ tembN,
    const float* __restrict__ Wat, const float* __restrict__ ba, float* __restrict__ att2,
    float* __restrict__ cmax, float* __restrict__ csum,
    const float* __restrict__ spart, const float* __restrict__ ga, const float* __restrict__ bea,
    const float* __restrict__ Wp, const float* __restrict__ bp, float* __restrict__ fiin,
    const float* __restrict__ resb, const float* __restrict__ Ws, const float* __restrict__ bsb,
    float* __restrict__ vecst_l, int nRate){
  __shared__ float As[32][68];
  __shared__ float Bs[64][68];
  __shared__ float OT[32][69];
  __shared__ float pm[4][64];
  __shared__ float cmv[64];
  int t = threadIdx.x;
  if ((int)blockIdx.x < nRate){
    int r0 = blockIdx.x*32;
    int tc = t & 15, tr = t >> 4;
    float acc[2][4] = {{0.f,0.f,0.f,0.f},{0.f,0.f,0.f,0.f}};
    for (int kc=0; kc<512; kc+=64){
#pragma unroll
      for (int i=0;i<2;i++){
        int idx = i*256 + t;
        int row = idx>>4, kq = idx&15;
        *reinterpret_cast<float4*>(&As[row][kq*4]) =
          *reinterpret_cast<const float4*>(tembN + (size_t)(r0+row)*512 + kc + kq*4);
      }
#pragma unroll
      for (int i=0;i<4;i++){
        int idx = i*256 + t;
        int k = idx>>4, hq = idx&15;
        *reinterpret_cast<float4*>(&Bs[k][hq*4]) =
          *reinterpret_cast<const float4*>(Wat + (size_t)(kc+k)*64 + hq*4);
      }
      __syncthreads();
#pragma unroll 8
      for (int k=0;k<64;++k){
        float a0 = As[tr*2+0][k];
        float a1 = As[tr*2+1][k];
        float4 bv = *reinterpret_cast<const float4*>(&Bs[k][tc*4]);
        acc[0][0]+=a0*bv.x; acc[0][1]+=a0*bv.y; acc[0][2]+=a0*bv.z; acc[0][3]+=a0*bv.w;
        acc[1][0]+=a1*bv.x; acc[1][1]+=a1*bv.y; acc[1][2]+=a1*bv.z; acc[1][3]+=a1*bv.w;
      }
      __syncthreads();
    }
    float4 bb = *reinterpret_cast<const float4*>(ba + tc*4);
#pragma unroll
    for (int j=0;j<2;j++){
      float4 o;
      o.x = fmaxf(acc[j][0]+bb.x, 0.f);
      o.y = fmaxf(acc[j][1]+bb.y, 0.f);
      o.z = fmaxf(acc[j][2]+bb.z, 0.f);
      o.w = fmaxf(acc[j][3]+bb.w, 0.f);
      *reinterpret_cast<float4*>(att2 + (size_t)(r0 + tr*2 + j)*64 + tc*4) = o;
      OT[tr*2+j][tc*4+0]=o.x; OT[tr*2+j][tc*4+1]=o.y;
      OT[tr*2+j][tc*4+2]=o.z; OT[tr*2+j][tc*4+3]=o.w;
    }
    __syncthreads();
    int h = t & 63, q = t >> 6;
    float m = -1e30f;
#pragma unroll
    for (int r=0;r<8;r++) m = fmaxf(m, OT[q*8+r][h]);
    pm[q][h] = m;
    __syncthreads();
    if (t < 64) cmv[t] = fmaxf(fmaxf(pm[0][t],pm[1][t]),fmaxf(pm[2][t],pm[3][t]));
    __syncthreads();
    float mm = cmv[h];
    float s = 0.f;
#pragma unroll
    for (int r=0;r<8;r++) s += __expf(OT[q*8+r][h]-mm);
    pm[q][h] = s;
    __syncthreads();
    if (t < 64){
      float ss = pm[0][t]+pm[1][t]+pm[2][t]+pm[3][t];
      cmax[(size_t)blockIdx.x*64 + t] = cmv[t];
      csum[(size_t)blockIdx.x*64 + t] = ss;
    }
  } else if ((int)blockIdx.x < nRate + 256){
    // ---- sln role: 4 waves, one (b,k) each ----
    int gid = blockIdx.x - nRate;
    int w = t>>6, lane = t&63;
    int bk = gid*4 + w;
    int b = bk>>6, k = bk&63;
    int d0 = lane*8;
    float sv[8];
#pragma unroll
    for (int j=0;j<8;j++) sv[j]=0.f;
#pragma unroll
    for (int lc=0;lc<4;lc++){
      const float* p = spart + ((size_t)((b*4+lc)*64 + k))*512 + d0;
      float4 x0 = *reinterpret_cast<const float4*>(p);
      float4 x1 = *reinterpret_cast<const float4*>(p+4);
      sv[0]+=x0.x; sv[1]+=x0.y; sv[2]+=x0.z; sv[3]+=x0.w;
      sv[4]+=x1.x; sv[5]+=x1.y; sv[6]+=x1.z; sv[7]+=x1.w;
    }
    const float inv_sqrt_L = 0.03125f;
    float s1=0.f, s2=0.f;
#pragma unroll
    for (int j=0;j<8;j++){ sv[j]*=inv_sqrt_L; s1+=sv[j]; s2+=sv[j]*sv[j]; }
    s1 = waveSumAll(s1); s2 = waveSumAll(s2);
    float m = s1*(1.0f/512.0f);
    float var = s2*(1.0f/512.0f) - m*m;
    float rstd = rsqrtf(var + 1e-5f);
    const float* gap = ga + (size_t)k*512 + d0;
    const float* bep = bea + (size_t)k*512 + d0;
    float4 g0 = *reinterpret_cast<const float4*>(gap);
    float4 g1 = *reinterpret_cast<const float4*>(gap+4);
    float4 e0 = *reinterpret_cast<const float4*>(bep);
    float4 e1 = *reinterpret_cast<const float4*>(bep+4);
    float gav[8] = {g0.x,g0.y,g0.z,g0.w,g1.x,g1.y,g1.z,g1.w};
    float bev[8] = {e0.x,e0.y,e0.z,e0.w,e1.x,e1.y,e1.z,e1.w};
    float acc[8];
#pragma unroll
    for (int e=0;e<8;e++) acc[e]=0.f;
#pragma unroll
    for (int j=0;j<8;j++){
      float sl = (sv[j]-m)*rstd*gav[j] + bev[j];
      const float* wp = Wp + ((size_t)k*512 + d0 + j)*8;
      float4 w0 = *reinterpret_cast<const float4*>(wp);
      float4 w1 = *reinterpret_cast<const float4*>(wp+4);
      acc[0]+=sl*w0.x; acc[1]+=sl*w0.y; acc[2]+=sl*w0.z; acc[3]+=sl*w0.w;
      acc[4]+=sl*w1.x; acc[5]+=sl*w1.y; acc[6]+=sl*w1.z; acc[7]+=sl*w1.w;
    }
#pragma unroll
    for (int e=0;e<8;e++) acc[e] = waveSum(acc[e]);
    if (lane==0){
#pragma unroll
      for (int e=0;e<8;e++)
        fiin[(size_t)b*512 + e*64 + k] = fmaxf(acc[e] + bp[k*8+e], 0.f);
    }
  } else {
    // ---- set(l-1) role ----
    float* row  = &As[0][0];
    float* part = &OT[0][0];
    int bsI = blockIdx.x - nRate - 256;
    int oc = bsI & 1, b = bsI >> 1;
    int og = t & 63, q = t >> 6;
    int o = oc*64 + og;
    reinterpret_cast<float2*>(row)[t] = reinterpret_cast<const float2*>(resb + (size_t)b*512)[t];
    __syncthreads();
    float acc = 0.f;
    const float* wp = Ws + (size_t)(q*128)*128 + o;
    const float* rp = &row[q*128];
#pragma unroll 4
    for (int d=0; d<128; ++d) acc += rp[d] * wp[(size_t)d*128];
    part[q*64+og] = acc;
    __syncthreads();
    if (q==0){
      vecst_l[(size_t)b*128 + o] = fmaxf(part[og]+part[64+og]+part[128+og]+part[192+og] + bsb[o], 0.f);
    }
  }
}

// ---- standalone FI (tail, layer 15) ----
__global__ __launch_bounds__(256) void k_fi(const float* __restrict__ fiin,
    const float* __restrict__ Wf, const float* __restrict__ bfi, float* __restrict__ res){
  int oc = blockIdx.x, b = blockIdx.y;
  int tid = threadIdx.x;
  int og = tid & 63, q = tid >> 6;
  int o = oc*64 + og;
  __shared__ float row[512];
  __shared__ float part[4][64];
  reinterpret_cast<float2*>(row)[tid] = reinterpret_cast<const float2*>(fiin + (size_t)b*512)[tid];
  __syncthreads();
  float acc = 0.f;
  const float* wp = Wf + (size_t)(q*128)*512 + o;
  const float* rp = &row[q*128];
#pragma unroll 4
  for (int d=0; d<128; ++d) acc += rp[d] * wp[(size_t)d*512];
  part[q][og] = acc;
  __syncthreads();
  if (q==0){
    float s = part[0][og]+part[1][og]+part[2][og]+part[3][og];
    res[(size_t)b*512 + o] = fmaxf(s + bfi[o], 0.f) + row[o];
  }
}

// ---- standalone Set (tail, layer 15) ----
__global__ __launch_bounds__(256) void k_set(const float* __restrict__ res,
    const float* __restrict__ Ws, const float* __restrict__ bs, float* __restrict__ vecst_l){
  int oc = blockIdx.x, b = blockIdx.y;
  int tid = threadIdx.x;
  int og = tid & 63, q = tid >> 6;
  int o = oc*64 + og;
  __shared__ float row[512];
  __shared__ float part[4][64];
  reinterpret_cast<float2*>(row)[tid] = reinterpret_cast<const float2*>(res + (size_t)b*512)[tid];
  __syncthreads();
  float acc = 0.f;
  const float* wp = Ws + (size_t)(q*128)*128 + o;
  const float* rp = &row[q*128];
#pragma unroll 4
  for (int d=0; d<128; ++d) acc += rp[d] * wp[(size_t)d*128];
  part[q][og] = acc;
  __syncthreads();
  if (q==0){
    vecst_l[(size_t)b*128 + o] = fmaxf(part[0][og]+part[1][og]+part[2][og]+part[3][og] + bs[o], 0.f);
  }
}

// ---- final attention rate (wave-per-row) ----
__global__ __launch_bounds__(256) void k_aat_rate(const float* __restrict__ temb,
    const float* __restrict__ w_aat, const float* __restrict__ b_aat, float* __restrict__ ratef){
  int w = threadIdx.x>>6, lane = threadIdx.x&63;
  int bl = blockIdx.x*4 + w;
  const float* rp = temb + (size_t)bl*512 + lane*8;
  float4 e0 = *reinterpret_cast<const float4*>(rp);
  float4 e1 = *reinterpret_cast<const float4*>(rp+4);
  const float* wp = w_aat + lane*8;
  float4 w0 = *reinterpret_cast<const float4*>(wp);
  float4 w1 = *reinterpret_cast<const float4*>(wp+4);
  float s = e0.x*w0.x+e0.y*w0.y+e0.z*w0.z+e0.w*w0.w
          + e1.x*w1.x+e1.y*w1.y+e1.z*w1.z+e1.w*w1.w;
  s = waveSum(s);
  if (lane==0) ratef[bl] = fmaxf(s + b_aat[0], 0.f);
}

// ---- softmax over a contiguous 1024-run per block ----
__global__ __launch_bounds__(256) void k_softmax_seq(float* __restrict__ ratef){
  int b = blockIdx.x; int tid = threadIdx.x;
  float* base = ratef + (size_t)b*1024;
  float4 v = reinterpret_cast<float4*>(base)[tid];
  float mx = fmaxf(fmaxf(v.x,v.y),fmaxf(v.z,v.w));
  __shared__ float red[8];
  int wave=tid>>6, lane=tid&63;
  float wm = waveMax(mx);
  if(lane==0) red[wave]=wm;
  __syncthreads();
  mx = fmaxf(fmaxf(red[0],red[1]),fmaxf(red[2],red[3]));
  v.x=__expf(v.x-mx); v.y=__expf(v.y-mx); v.z=__expf(v.z-mx); v.w=__expf(v.w-mx);
  float s = v.x+v.y+v.z+v.w;
  float wsum = waveSum(s);
  if(lane==0) red[4+wave]=wsum;
  __syncthreads();
  s = red[4]+red[5]+red[6]+red[7];
  float inv = 1.f/s;
  v.x*=inv;v.y*=inv;v.z*=inv;v.w*=inv;
  reinterpret_cast<float4*>(base)[tid] = v;
}

// ---- final pool partials ----
__global__ __launch_bounds__(256) void k_poolA(const float* __restrict__ temb, const float* __restrict__ attf,
                                               float* __restrict__ sraw){
  int dc = blockIdx.x, b = blockIdx.y;
  int tid = threadIdx.x;
  int dl = tid & 63, q = tid >> 6;
  int d = dc*64 + dl;
  __shared__ float sA[1024];
  __shared__ float part[4][64];
  reinterpret_cast<float4*>(sA)[tid] = reinterpret_cast<const float4*>(attf + (size_t)b*1024)[tid];
  __syncthreads();
  float acc = 0.f;
  const float* tp = temb + ((size_t)b*1024 + q*256)*512 + d;
  const float* ap = &sA[q*256];
#pragma unroll 4
  for (int l=0;l<256;++l) acc += tp[(size_t)l*512]*ap[l];
  part[q][dl] = acc;
  __syncthreads();
  if (q==0) sraw[(size_t)b*512 + d] = (part[0][dl]+part[1][dl]+part[2][dl]+part[3][dl])*0.03125f;
}

// ---- final pool LN ----
__global__ __launch_bounds__(256) void k_poolB(const float* __restrict__ sraw,
   const float* __restrict__ g_aat, const float* __restrict__ be_aat, float* __restrict__ spool){
  int b = blockIdx.x; int tid = threadIdx.x;
  int d0 = tid*2;
  float2 a = *reinterpret_cast<const float2*>(&sraw[(size_t)b*512 + d0]);
  __shared__ float red[8];
  int wave=tid>>6,lane=tid&63;
  float s1 = a.x+a.y, s2 = a.x*a.x+a.y*a.y;
  float w1=waveSum(s1), w2=waveSum(s2);
  if(lane==0){red[wave]=w1; red[4+wave]=w2;}
  __syncthreads();
  s1=red[0]+red[1]+red[2]+red[3];
  s2=red[4]+red[5]+red[6]+red[7];
  float m=s1*(1.f/512.f), var=s2*(1.f/512.f)-m*m, rstd=rsqrtf(var+1e-5f);
  float2 ug=*reinterpret_cast<const float2*>(g_aat+d0);
  float2 ub=*reinterpret_cast<const float2*>(be_aat+d0);
  spool[(size_t)b*512+d0]   = (a.x-m)*rstd*ug.x+ub.x;
  spool[(size_t)b*512+d0+1] = (a.y-m)*rstd*ug.y+ub.y;
}

// ---- final head ----
__global__ __launch_bounds__(256) void k_final(const float* __restrict__ spool, const float* __restrict__ vecst,
    const float* __restrict__ Wh, const float* __restrict__ bh, float* __restrict__ Pout){
  int b = blockIdx.x; int tid = threadIdx.x;
  float part = 0.f;
  for (int i = tid; i < 2560; i += 256){
    float v;
    if (i < 512) v = spool[(size_t)b*512 + i];
    else {
      int j = i - 512;
      v = vecst[(size_t)(j>>7)*(B_*SET_) + b*SET_ + (j&127)];
    }
    part += v * Wh[i];
  }
  __shared__ float red[4];
  int wave=tid>>6,lane=tid&63;
  float w = waveSum(part);
  if(lane==0) red[wave]=w;
  __syncthreads();
  if (tid==0){
    float x = red[0]+red[1]+red[2]+red[3] + bh[0];
    Pout[b] = 1.0f/(1.0f+expf(-x));
  }
}

extern "C" void kernel_launch(void* const* d_in, const int* in_sizes, int n_in,
                              void* d_out, int out_size, void* d_ws, size_t ws_size,
                              hipStream_t stream){
  const float* emb   = (const float*)d_in[0];
  const float* W_att = (const float*)d_in[1];
  const float* b_att = (const float*)d_in[2];
  const float* g_att = (const float*)d_in[3];
  const float* be_att= (const float*)d_in[4];
  const float* W_pro = (const float*)d_in[5];
  const float* b_pro = (const float*)d_in[6];
  const float* w_p1  = (const float*)d_in[7];
  const float* b_p1  = (const float*)d_in[8];
  const float* W_FI  = (const float*)d_in[9];
  const float* b_FI  = (const float*)d_in[10];
  const float* W_Set = (const float*)d_in[11];
  const float* b_Set = (const float*)d_in[12];
  const float* g_n   = (const float*)d_in[13];
  const float* be_n  = (const float*)d_in[14];
  const float* w_aat = (const float*)d_in[15];
  const float* b_aat = (const float*)d_in[16];
  const float* g_aat = (const float*)d_in[17];
  const float* be_aat= (const float*)d_in[18];
  const float* W_h2p = (const float*)d_in[19];
  const float* b_h2p = (const float*)d_in[20];
  float* out = (float*)d_out;

  float* ws = (float*)d_ws;
  float* temb0 = ws;                      // 8,388,608
  float* temb1 = temb0 + 8388608;         // 8,388,608
  float* att2  = temb1 + 8388608;         // 1,048,576
  float* spart = att2 + 1048576;          // 2,097,152
  float* fiin  = spart + 2097152;         // 8,192
  float* vecst = fiin + 8192;             // 131,072
  float* ratef = vecst + 131072;          // 16,384
  float* spool = ratef + 16384;           // 8,192
  float* res   = spool + 8192;            // 8,192
  float* sraw  = res + 8192;              // 8,192
  float* Wat   = sraw + 8192;             // 524,288
  float* cmaxA = Wat + 524288;            // 32,768
  float* csumA = cmaxA + 32768;           // 32,768

  k_wt<<<16,256,0,stream>>>(W_att, Wat);
  k_rate_gemm<<<512,256,0,stream>>>(emb, Wat, b_att, att2, cmaxA, csumA);
  for (int l=0; l<16; ++l){
    const float* tcur = (l==0) ? emb : ((l&1) ? temb0 : temb1);
    float* tnxt = (l&1) ? temb1 : temb0;
    int nFi = (l>0) ? 128 : 0;
    int lprev = (l>0) ? (l-1) : 0;
    k_su<<<1024+nFi,256,0,stream>>>(tcur, tnxt, att2, cmaxA, csumA, spart,
                                    w_p1 + l*512, b_p1 + l*512, g_n + l*512, be_n + l*512,
                                    out + 16, l,
                                    fiin, W_FI + (size_t)lprev*262144, b_FI + lprev*512, res);
    int nRate = (l < 15) ? 512 : 0;
    int nSet = (l>0) ? 32 : 0;
    k_ratesln<<<nRate + 256 + nSet,256,0,stream>>>(tnxt, Wat + (size_t)(l+1)*32768, b_att + (l+1)*64,
                                            att2, cmaxA, csumA,
                                            spart, g_att + (size_t)l*32768, be_att + (size_t)l*32768,
                                            W_pro + (size_t)l*262144, b_pro + l*512, fiin,
                                            res, W_Set + (size_t)lprev*65536, b_Set + lprev*128,
                                            vecst + (size_t)lprev*2048, nRate);
  }
  // tail: fi(15) + set(15)
  k_fi<<<dim3(8,16),256,0,stream>>>(fiin, W_FI + (size_t)15*262144, b_FI + 15*512, res);
  k_set<<<dim3(2,16),256,0,stream>>>(res, W_Set + (size_t)15*65536, b_Set + 15*128,
                                     vecst + (size_t)15*2048);
  float* tfin = temb1;   // layer 15 writes temb1
  k_aat_rate<<<4096,256,0,stream>>>(tfin, w_aat, b_aat, ratef);
  k_softmax_seq<<<16,256,0,stream>>>(ratef);
  k_poolA<<<dim3(8,16),256,0,stream>>>(tfin, ratef, sraw);
  k_poolB<<<16,256,0,stream>>>(sraw, g_aat, be_aat, spool);
  k_final<<<16,256,0,stream>>>(spool, vecst, W_h2p, b_h2p, out);
}